// Round 2
// baseline (14.063 us; speedup 1.0000x reference)
//
#include <hip/hip_runtime.h>

// RTL (random tiny lattice) layer:
//   x: (2048, 128) f32, kernel: (81, 1024) f32, indices: (1024, 4) i32
//   out[b,l] = 16-point multilinear interp of kernel[:, l] at x[b, idx[l,:]]
//
// Vertex index v = 27*v0 + 9*v1 + 3*v2 + v3. The 16 needed vertices are
// 4 clusters {u, u+1, u+3, u+4}, u = 9*(m0+3a+b) + 3*i2 + i3, a,b in {0,1}.
// We pre-stage every possible cluster as a contiguous float4 in LDS:
//   Kq[q][l] = (K[u],K[u+1],K[u+3],K[u+4]),  q = 4*m + (2*i2+i3), m=u/9
// -> per output only 4x ds_read_b128 with immediate offsets, conflict-free
//    (bank = 4*lane mod 32, independent of data-dependent q).

#define NFEAT   128
#define NLAT    1024
#define BATCH   2048
#define LT      64    // lattices per block (= wave width)
#define BT      32    // batch rows per block
#define THREADS 256
#define NQUAD   36    // 9 m-values * 4 (i2,i3) combos

__global__ __launch_bounds__(THREADS, 4)
void rtl_kernel(const float* __restrict__ x,
                const float* __restrict__ kern,
                const int*   __restrict__ indices,
                float*       __restrict__ out) {
    __shared__ float4 Kq[NQUAD * LT];   // 36 KB

    const int tid   = threadIdx.x;
    const int ltile = blockIdx.x & 15;   // 16 lattice tiles
    const int btile = blockIdx.x >> 4;   // 64 batch tiles
    const int l0    = ltile * LT;
    const int b0    = btile * BT;

    // ---- stage quad-replicated kernel slice (9 iters/thread, coalesced) ----
    for (int i = tid; i < NQUAD * LT; i += THREADS) {
        const int q  = i >> 6;          // quad id
        const int l  = i & (LT - 1);    // lattice within tile
        const int m  = q >> 2;
        const int jj = q & 3;           // 2*i2 + i3
        const int u  = 9 * m + 3 * (jj >> 1) + (jj & 1);
        const float* kp = kern + u * NLAT + l0 + l;
        Kq[i] = make_float4(kp[0], kp[NLAT], kp[3 * NLAT], kp[4 * NLAT]);
    }

    const int lane = tid & 63;
    const int wid  = __builtin_amdgcn_readfirstlane(tid >> 6);  // wave id 0..3
    const int4 idx = *(const int4*)(indices + (l0 + lane) * 4);

    __syncthreads();

    const float4* col = Kq + lane;      // thread's lattice column; element q at col[q*64]

    // each wave owns 8 consecutive batch rows
#pragma unroll 2
    for (int k = 0; k < 8; ++k) {
        const int bi = wid * 8 + k;
        const float* xr = x + (b0 + bi) * NFEAT;   // wave-uniform base -> SGPR

        float x0 = fminf(fmaxf(xr[idx.x], 0.0f), 2.0f);
        float x1 = fminf(fmaxf(xr[idx.y], 0.0f), 2.0f);
        float x2 = fminf(fmaxf(xr[idx.z], 0.0f), 2.0f);
        float x3 = fminf(fmaxf(xr[idx.w], 0.0f), 2.0f);

        // cell bit i_r = (x_r >= 1), fractional t_r = x_r - i_r
        const int  i0 = (x0 >= 1.0f);  const float t0 = x0 - (float)i0;
        const int  i1 = (x1 >= 1.0f);  const float t1 = x1 - (float)i1;
        const int  i2 = (x2 >= 1.0f);  const float t2 = x2 - (float)i2;
        const int  i3 = (x3 >= 1.0f);  const float t3 = x3 - (float)i3;

        // base quad: q00 = 4*(3*i0 + i1) + 2*i2 + i3
        const int q00 = 12 * i0 + 4 * i1 + 2 * i2 + i3;
        const float4* cq = col + q00 * LT;

        // 4 clusters: (a,b) = (0,0),(0,1),(1,0),(1,1) -> quad offsets 0,4,12,16
        const float4 fA = cq[0];
        const float4 fB = cq[4 * LT];
        const float4 fC = cq[12 * LT];
        const float4 fD = cq[16 * LT];

        // innermost lerp over dim3 (t3), then dim2 (t2) within each cluster
        const float eA0 = fmaf(t3, fA.y - fA.x, fA.x);
        const float eA1 = fmaf(t3, fA.w - fA.z, fA.z);
        const float cA  = fmaf(t2, eA1 - eA0, eA0);
        const float eB0 = fmaf(t3, fB.y - fB.x, fB.x);
        const float eB1 = fmaf(t3, fB.w - fB.z, fB.z);
        const float cB  = fmaf(t2, eB1 - eB0, eB0);
        const float eC0 = fmaf(t3, fC.y - fC.x, fC.x);
        const float eC1 = fmaf(t3, fC.w - fC.z, fC.z);
        const float cC  = fmaf(t2, eC1 - eC0, eC0);
        const float eD0 = fmaf(t3, fD.y - fD.x, fD.x);
        const float eD1 = fmaf(t3, fD.w - fD.z, fD.z);
        const float cD  = fmaf(t2, eD1 - eD0, eD0);

        // dim1 (t1) over b, dim0 (t0) over a
        const float n0  = fmaf(t1, cB - cA, cA);
        const float n1  = fmaf(t1, cD - cC, cC);
        const float res = fmaf(t0, n1 - n0, n0);

        out[(b0 + bi) * NLAT + l0 + lane] = res;
    }
}

extern "C" void kernel_launch(void* const* d_in, const int* in_sizes, int n_in,
                              void* d_out, int out_size, void* d_ws, size_t ws_size,
                              hipStream_t stream) {
    const float* x       = (const float*)d_in[0];
    const float* kern    = (const float*)d_in[1];
    const int*   indices = (const int*)d_in[2];
    float*       out     = (float*)d_out;

    const int grid = (NLAT / LT) * (BATCH / BT);  // 16 * 64 = 1024 blocks = 4/CU
    rtl_kernel<<<grid, THREADS, 0, stream>>>(x, kern, indices, out);
}

// Round 3
// 12.037 us; speedup vs baseline: 1.1684x; 1.1684x over previous
//
#include <hip/hip_runtime.h>

// RTL (random tiny lattice) layer:
//   x: (2048, 128) f32, kernel: (81, 1024) f32, indices: (1024, 4) i32
//   out[b,l] = 16-point multilinear interp of kernel[:, l] at x[b, idx[l,:]]
//
// Vertex v = 27v0+9v1+3v2+v3. The 16 needed vertices form 4 clusters
// {u,u+1,u+3,u+4}, u = 9*(3*i0+i1+3a+b) + 3*i2+i3, (a,b) in {0,1}^2.
// Pre-stage every possible cluster as a contiguous float4 in LDS:
//   Kq[q][l], q = 4*m + (2*i2+i3), m = 0..8  ->  36 quads, 36 KB.
// Inner loop per output: 4x ds_read_b128 (imm offsets, conflict-free:
// bank = 4*lane mod 32, independent of data-dependent q) + 4x ds_read_b32
// x-gathers from an LDS-staged x tile. No global latency in the loop.

#define NFEAT   128
#define NLAT    1024
#define BATCH   2048
#define LT      64     // lattices per block (= wave width)
#define BT      64     // batch rows per block
#define THREADS 512
#define NQUAD   36

__global__ __launch_bounds__(THREADS, 4)   // 4 waves/EU -> 2 blocks/CU
void rtl_kernel(const float* __restrict__ x,
                const float* __restrict__ kern,
                const int*   __restrict__ indices,
                float*       __restrict__ out) {
    __shared__ float4 Kq[NQUAD * LT];   // 36 KB
    __shared__ float  Xl[BT * NFEAT];   // 32 KB

    const int tid   = threadIdx.x;
    const int ltile = blockIdx.x & 15;   // 16 lattice tiles
    const int btile = blockIdx.x >> 4;   // 32 batch tiles
    const int l0    = ltile * LT;
    const int b0    = btile * BT;

    // ---- stage x tile: 64 rows x 128 f32 = 2048 float4, fully coalesced ----
    {
        float4* dst = (float4*)Xl;
        const float4* src = (const float4*)(x + b0 * NFEAT);
        #pragma unroll
        for (int i = tid; i < (BT * NFEAT) / 4; i += THREADS) dst[i] = src[i];
    }
    // ---- stage quad-replicated kernel slice (~4.5 float4 per thread) ----
    for (int i = tid; i < NQUAD * LT; i += THREADS) {
        const int q  = i >> 6;
        const int l  = i & (LT - 1);
        const int m  = q >> 2;
        const int jj = q & 3;            // 2*i2 + i3
        const int u  = 9 * m + 3 * (jj >> 1) + (jj & 1);
        const float* kp = kern + u * NLAT + l0 + l;
        Kq[i] = make_float4(kp[0], kp[NLAT], kp[3 * NLAT], kp[4 * NLAT]);
    }

    const int lane = tid & 63;
    const int wid  = tid >> 6;           // wave id 0..7, owns 8 batch rows
    const int4 idx = *(const int4*)(indices + (l0 + lane) * 4);

    __syncthreads();

    const float4* col = Kq + lane;       // element q at col[q*64]
    float* orow = out + (b0 + wid * 8) * NLAT + l0 + lane;

#pragma unroll 2
    for (int k = 0; k < 8; ++k) {
        const float* xr = Xl + (wid * 8 + k) * NFEAT;

        float x0 = fminf(fmaxf(xr[idx.x], 0.0f), 2.0f);
        float x1 = fminf(fmaxf(xr[idx.y], 0.0f), 2.0f);
        float x2 = fminf(fmaxf(xr[idx.z], 0.0f), 2.0f);
        float x3 = fminf(fmaxf(xr[idx.w], 0.0f), 2.0f);

        const int  i0 = (x0 >= 1.0f);  const float t0 = x0 - (float)i0;
        const int  i1 = (x1 >= 1.0f);  const float t1 = x1 - (float)i1;
        const int  i2 = (x2 >= 1.0f);  const float t2 = x2 - (float)i2;
        const int  i3 = (x3 >= 1.0f);  const float t3 = x3 - (float)i3;

        const int q00 = 12 * i0 + 4 * i1 + 2 * i2 + i3;
        const float4* cq = col + q00 * LT;

        // clusters (a,b): +0, +4 (b=1), +12 (a=1), +16 (a=1,b=1) quads
        const float4 fA = cq[0];
        const float4 fB = cq[4 * LT];
        const float4 fC = cq[12 * LT];
        const float4 fD = cq[16 * LT];

        const float eA0 = fmaf(t3, fA.y - fA.x, fA.x);
        const float eA1 = fmaf(t3, fA.w - fA.z, fA.z);
        const float cA  = fmaf(t2, eA1 - eA0, eA0);
        const float eB0 = fmaf(t3, fB.y - fB.x, fB.x);
        const float eB1 = fmaf(t3, fB.w - fB.z, fB.z);
        const float cB  = fmaf(t2, eB1 - eB0, eB0);
        const float eC0 = fmaf(t3, fC.y - fC.x, fC.x);
        const float eC1 = fmaf(t3, fC.w - fC.z, fC.z);
        const float cC  = fmaf(t2, eC1 - eC0, eC0);
        const float eD0 = fmaf(t3, fD.y - fD.x, fD.x);
        const float eD1 = fmaf(t3, fD.w - fD.z, fD.z);
        const float cD  = fmaf(t2, eD1 - eD0, eD0);

        const float n0  = fmaf(t1, cB - cA, cA);
        const float n1  = fmaf(t1, cD - cC, cC);
        const float res = fmaf(t0, n1 - n0, n0);

        orow[k * NLAT] = res;
    }
}

extern "C" void kernel_launch(void* const* d_in, const int* in_sizes, int n_in,
                              void* d_out, int out_size, void* d_ws, size_t ws_size,
                              hipStream_t stream) {
    const float* x       = (const float*)d_in[0];
    const float* kern    = (const float*)d_in[1];
    const int*   indices = (const int*)d_in[2];
    float*       out     = (float*)d_out;

    const int grid = (NLAT / LT) * (BATCH / BT);  // 16 * 32 = 512 = 2 per CU
    rtl_kernel<<<grid, THREADS, 0, stream>>>(x, kern, indices, out);
}